// Round 15
// baseline (1939.402 us; speedup 1.0000x reference)
//
#include <hip/hip_runtime.h>

typedef unsigned short u16;
typedef unsigned int   u32;
typedef unsigned long long u64;
typedef __attribute__((ext_vector_type(8)))  short  short8v;   // 8 x bf16 (as i16)
typedef __attribute__((ext_vector_type(4)))  float  f32x4;
typedef __attribute__((ext_vector_type(4)))  unsigned short ushort4v;
typedef __attribute__((ext_vector_type(4)))  u32 u32x4;

#define B_   32
#define T_   512
#define D_   1024
#define N4_  4096
#define NWG  256         // scan WGs: 128 unit-groups (8 units) x 2 batch halves (16 rows)

// ---- workspace layout (bytes) ----
#define OFF_XN   0ull                 // xn bf16   [32*512*1024]      33554432
#define OFF_ZX   33554432ull          // Zx bf16   [512][32][1024][4] 134217728  (gate-interleaved)
#define OFF_KT   167772160ull         // kernel^T bf16 [4096][1024]    8388608  (reused as h_last after GEMM)
#define OFF_RT   176160768ull         // recurrent^T bf16 [4096][1024] 8388608
#define OFF_HB   184549376ull         // h double buffer bf16 2*[32][1024] = 131072
#define OFF_FLG  184680448ull         // flags: 512 x 64B-strided u32 (2 gate-wave flags per WG)

__device__ inline u16 f2bf(float f) {
  union { float f; u32 u; } x; x.f = f;
  u32 r = x.u + 0x7FFFu + ((x.u >> 16) & 1u);   // RNE
  return (u16)(r >> 16);
}
__device__ inline float bf2f(u16 h) {
  union { u32 u; float f; } x; x.u = ((u32)h) << 16; return x.f;
}
__device__ inline float sigm(float x) { return 1.f / (1.f + __expf(-x)); }
__device__ inline float tanh_fast(float x) {
  float e = __expf(2.f * x);
  return 1.f - 2.f / (e + 1.f);
}

// ---------------- init: zero h buffers + flags ----------------
__global__ __launch_bounds__(256) void init_kernel(u32* hbuf, u32* flags) {
  int i = blockIdx.x * 256 + threadIdx.x;
  if (i < 32768) hbuf[i] = 0u;       // both parities: 2*32*1024 bf16 = 32768 dwords
  if (i < 512)   flags[i * 16] = 0u;
}

// ---------------- LN1: x fp32 -> xn bf16 ----------------
__global__ __launch_bounds__(256) void ln1_kernel(const float* __restrict__ x,
    const float* __restrict__ gam, const float* __restrict__ bet, u16* __restrict__ xn) {
  int row = blockIdx.x; int tid = threadIdx.x;
  const float* xr = x + (size_t)row * D_;
  float4 v = *(const float4*)(xr + tid * 4);
  float s  = v.x + v.y + v.z + v.w;
  float ss = v.x*v.x + v.y*v.y + v.z*v.z + v.w*v.w;
  #pragma unroll
  for (int o = 32; o > 0; o >>= 1) { s += __shfl_down(s, o); ss += __shfl_down(ss, o); }
  __shared__ float red[8];
  int w = tid >> 6, l = tid & 63;
  if (l == 0) { red[w] = s; red[4 + w] = ss; }
  __syncthreads();
  s  = red[0] + red[1] + red[2] + red[3];
  ss = red[4] + red[5] + red[6] + red[7];
  float mean = s * (1.f / D_);
  float var  = ss * (1.f / D_) - mean * mean;
  float rstd = rsqrtf(var + 1e-3f);
  float4 g = *(const float4*)(gam + tid * 4);
  float4 b = *(const float4*)(bet + tid * 4);
  ushort4v o4;
  o4.x = f2bf((v.x - mean) * rstd * g.x + b.x);
  o4.y = f2bf((v.y - mean) * rstd * g.y + b.y);
  o4.z = f2bf((v.z - mean) * rstd * g.z + b.z);
  o4.w = f2bf((v.w - mean) * rstd * g.w + b.w);
  *(ushort4v*)(xn + (size_t)row * D_ + tid * 4) = o4;
}

// ---------------- transpose [1024][4096] fp32 -> [4096][1024] bf16 ----------------
__global__ __launch_bounds__(256) void transpose_bf16(const float* __restrict__ W, u16* __restrict__ WT) {
  __shared__ float tile[32][33];
  int c0 = blockIdx.x * 32, r0 = blockIdx.y * 32;
  int tx = threadIdx.x, ty = threadIdx.y;
  #pragma unroll
  for (int i = ty; i < 32; i += 8)
    tile[i][tx] = W[(size_t)(r0 + i) * N4_ + c0 + tx];
  __syncthreads();
  #pragma unroll
  for (int i = ty; i < 32; i += 8)
    WT[(size_t)(c0 + i) * D_ + r0 + tx] = f2bf(tile[tx][i]);
}

// ---------------- GEMM: Zx = xn @ kernel + bias  (gate-interleaved output) ----------------
__global__ __launch_bounds__(256) void gemm_xk(const u16* __restrict__ A, const u16* __restrict__ Bt,
    const float* __restrict__ bias, u16* __restrict__ Zx) {
  __shared__ u16 As[128 * 32];
  __shared__ u16 Bs[128 * 32];
  int tid = threadIdx.x;
  int bm = blockIdx.x >> 5, bn = blockIdx.x & 31;
  int w = tid >> 6, l = tid & 63;
  int srow = tid >> 2, sk = (tid & 3) * 8;        // staging: row j*64+srow, k = sk..sk+8
  const u16* Ag = A  + (size_t)(bm * 128 + srow) * D_ + sk;
  const u16* Bg = Bt + (size_t)(bn * 128 + srow) * D_ + sk;
  int sb0 = (srow * 64 + sk * 2)          ^ ((srow & 3) << 4);
  int sb1 = ((srow + 64) * 64 + sk * 2)   ^ ((srow & 3) << 4);
  int wm = w >> 1, wn = w & 1;
  int frow = l & 15, fko = (l >> 4) * 16;         // fragment k byte offset
  f32x4 acc[4][4];
  #pragma unroll
  for (int mi = 0; mi < 4; ++mi)
    #pragma unroll
    for (int ni = 0; ni < 4; ++ni)
      #pragma unroll
      for (int j = 0; j < 4; ++j) acc[mi][ni][j] = 0.f;

  short8v ap0 = *(const short8v*)(Ag);
  short8v ap1 = *(const short8v*)(Ag + 64 * (size_t)D_);
  short8v bp0 = *(const short8v*)(Bg);
  short8v bp1 = *(const short8v*)(Bg + 64 * (size_t)D_);

  for (int kt = 0; kt < 32; ++kt) {
    __syncthreads();
    *(short8v*)((char*)As + sb0) = ap0;
    *(short8v*)((char*)As + sb1) = ap1;
    *(short8v*)((char*)Bs + sb0) = bp0;
    *(short8v*)((char*)Bs + sb1) = bp1;
    __syncthreads();
    if (kt < 31) {
      ap0 = *(const short8v*)(Ag + (kt + 1) * 32);
      ap1 = *(const short8v*)(Ag + 64 * (size_t)D_ + (kt + 1) * 32);
      bp0 = *(const short8v*)(Bg + (kt + 1) * 32);
      bp1 = *(const short8v*)(Bg + 64 * (size_t)D_ + (kt + 1) * 32);
    }
    short8v af[4], bfr[4];
    #pragma unroll
    for (int mi = 0; mi < 4; ++mi) {
      int r = wm * 64 + mi * 16 + frow;
      af[mi] = *(const short8v*)((char*)As + ((r * 64 + fko) ^ ((r & 3) << 4)));
    }
    #pragma unroll
    for (int ni = 0; ni < 4; ++ni) {
      int r = wn * 64 + ni * 16 + frow;
      bfr[ni] = *(const short8v*)((char*)Bs + ((r * 64 + fko) ^ ((r & 3) << 4)));
    }
    #pragma unroll
    for (int mi = 0; mi < 4; ++mi)
      #pragma unroll
      for (int ni = 0; ni < 4; ++ni)
        acc[mi][ni] = __builtin_amdgcn_mfma_f32_16x16x32_bf16(af[mi], bfr[ni], acc[mi][ni], 0, 0, 0);
  }
  // epilogue: +bias, bf16, remap rows to [t][b] and cols to [unit][gate]
  #pragma unroll
  for (int mi = 0; mi < 4; ++mi) {
    #pragma unroll
    for (int ni = 0; ni < 4; ++ni) {
      int col = bn * 128 + wn * 64 + ni * 16 + (l & 15);
      float bv = bias[col];
      int colp = ((col & 1023) << 2) | (col >> 10);   // gate-interleaved
      #pragma unroll
      for (int j = 0; j < 4; ++j) {
        int row = bm * 128 + wm * 64 + mi * 16 + (l >> 4) * 4 + j;
        int zrow = (row & 511) * 32 + (row >> 9);
        Zx[(size_t)zrow * N4_ + colp] = f2bf(acc[mi][ni][j] + bv);
      }
    }
  }
}

// ---------------- persistent LSTM scan (R15: fine-grained dataflow) ----------------
// 256 WGs x 512 thr = 128 unit-groups (8 units) x 2 batch halves (16 rows).
// NO h LDS staging: each wave's MFMA A-fragment is a direct strided global read
// of its own (16-row x 128-unit) h slice (4 x 16B sc0/sc1 per lane).
// Per-gate-wave flags (flag[wg*2+gw], 512): wave ks polls ONLY its 32 producer
// flags (16 source unit-groups x 2 gate waves, same batch half) and proceeds
// independently. ONE barrier/step (z-write -> gate read); z_lds parity-double-
// buffered. Safety: union of a WG's 8 waves' sources = all 128 same-bh WGs and
// all waves pass the barrier before gates publish => no parity overwrite races.
__global__ __launch_bounds__(512) __attribute__((amdgpu_waves_per_eu(2, 2)))
void lstm_scan(const u16* __restrict__ Zx,
    const u16* __restrict__ RT, u16* hbuf, float* h_last, u32* flags) {
  __shared__ float z_lds[2][8 * 16 * 36];    // 2 x 18 KB, parity-buffered
  int tid = threadIdx.x;
  int wg = blockIdx.x;
  int ug = wg >> 1, bh = wg & 1;             // unit-group, batch half
  int w = tid >> 6, l = tid & 63;
  int ks = w;                                // K-split: units ks*128..+128
  int fr = l & 15, hi = l >> 4;              // fragment row 0..15, k-quarter 0..3

  // B fragments (R^T): col c = ch*16+fr -> unit ug*8+(c>>2), gate c&3
  short8v b[4][2];
  #pragma unroll
  for (int ch = 0; ch < 2; ++ch) {
    int c = ch * 16 + fr;
    const u16* Rp = RT + (size_t)((c & 3) * 1024 + ug * 8 + (c >> 2)) * D_
                  + ks * 128 + hi * 8;
    #pragma unroll
    for (int kt = 0; kt < 4; ++kt) b[kt][ch] = *(const short8v*)(Rp + kt * 32);
  }
  #pragma unroll
  for (int kt = 0; kt < 4; ++kt) {
    asm volatile("" : "+v"(b[kt][0]));
    asm volatile("" : "+v"(b[kt][1]));
  }

  // direct-global A-fragment byte offset (within parity buffer):
  // row bh*16+fr (stride 2KB), k bytes = ks*256 + hi*16 (+ kt*64)
  int aoff = (bh * 16 + fr) * 2048 + ks * 256 + hi * 16;
  // gate cell (tid < 128): local batch row grow (0..15), unit gu (0..7)
  int grow = tid >> 3, gu = tid & 7;
  const u16* zx_p = Zx + (size_t)(bh * 16 + grow) * N4_ + (ug * 8 + gu) * 4;
  int hoff = (bh * 16 + grow) * D_ + ug * 8 + gu;
  float c = 0.f;
  // per-wave poll: lane n<32 watches source ug' = 16*ks + (n>>1), gate-wave n&1
  const u32* fpp = flags + (size_t)((((16 * ks + ((l & 31) >> 1)) * 2 + bh) * 2) + (l & 1)) * 16;

  #pragma unroll 1
  for (int t = 0; t < T_; ++t) {
    // prefetch this unit's 4 gate pre-activations (tid<128): one 8B load
    u64 zq = 0;
    if (tid < 128) zq = *(const u64*)(zx_p + (size_t)t * B_ * N4_);
    __builtin_amdgcn_sched_barrier(0);

    // per-wave poll of its 32 producer flags (lanes >=32 vacuously pass)
    {
      u32 t32 = (u32)t;
      while (true) {
        u32 f = (l < 32)
          ? __hip_atomic_load(fpp, __ATOMIC_RELAXED, __HIP_MEMORY_SCOPE_AGENT)
          : t32;
        if (__all((int)(f >= t32))) break;
      }
    }
    __builtin_amdgcn_sched_barrier(0);

    // A-fragments: 4 x 16B coherent loads direct from hbuf (no LDS staging)
    const char* ab = (const char*)hbuf + (size_t)(t & 1) * 65536 + aoff;
    short8v av[4];
    #pragma unroll
    for (int kt = 0; kt < 4; ++kt) {
      const char* p = ab + kt * 64;
      asm volatile("global_load_dwordx4 %0, %1, off sc0 sc1"
                   : "=&v"(av[kt]) : "v"(p) : "memory");
    }
    asm volatile("s_waitcnt vmcnt(0)" ::: "memory");
    __builtin_amdgcn_sched_barrier(0);

    // K-loop: 4 K-steps x 2 mfma 16x16x32
    f32x4 acc0, acc1;
    #pragma unroll
    for (int i = 0; i < 4; ++i) { acc0[i] = 0.f; acc1[i] = 0.f; }
    #pragma unroll
    for (int kt = 0; kt < 4; ++kt) {
      acc0 = __builtin_amdgcn_mfma_f32_16x16x32_bf16(av[kt], b[kt][0], acc0, 0, 0, 0);
      acc1 = __builtin_amdgcn_mfma_f32_16x16x32_bf16(av[kt], b[kt][1], acc1, 0, 0, 0);
    }
    // write K-partials into parity buffer: 16x16 D layout row=hi*4+j, col=fr
    float* zp = z_lds[t & 1];
    #pragma unroll
    for (int j = 0; j < 4; ++j) {
      int rowD = hi * 4 + j;
      zp[(ks * 16 + rowD) * 36 + fr]      = acc0[j];
      zp[(ks * 16 + rowD) * 36 + 16 + fr] = acc1[j];
    }
    __syncthreads();   // the ONE barrier: z visible to gate waves

    // gates: waves 0-1 only; waves 2-7 loop straight to the next poll
    if (tid < 128) {
      float z0 = bf2f((u16)(zq        & 0xFFFFu));
      float z1 = bf2f((u16)((zq >> 16) & 0xFFFFu));
      float z2 = bf2f((u16)((zq >> 32) & 0xFFFFu));
      float z3 = bf2f((u16)((zq >> 48) & 0xFFFFu));
      #pragma unroll
      for (int kss = 0; kss < 8; ++kss) {
        f32x4 zr = *(const f32x4*)&zp[(kss * 16 + grow) * 36 + gu * 4];
        z0 += zr[0]; z1 += zr[1]; z2 += zr[2]; z3 += zr[3];
      }
      float cn = sigm(z1) * c + sigm(z0) * tanh_fast(z2);
      float hn = sigm(z3) * tanh_fast(cn);
      c = cn;

      // publish h (pair adjacent units -> u32 agent-scope store)
      u32 hw = (u32)f2bf(hn);
      u32 nb = __shfl_down(hw, 1);
      if (!(gu & 1)) {
        u32* dst = (u32*)(hbuf + (size_t)((t + 1) & 1) * (B_ * D_) + hoff);
        __hip_atomic_store(dst, hw | (nb << 16), __ATOMIC_RELAXED, __HIP_MEMORY_SCOPE_AGENT);
      }
      if (t == T_ - 1) h_last[hoff] = hn;
      // drain this gate wave's h stores, then set ITS flag
      asm volatile("s_waitcnt vmcnt(0)" ::: "memory");
      if (l == 0)
        __hip_atomic_store(flags + (size_t)(wg * 2 + w) * 16, (u32)(t + 1),
                           __ATOMIC_RELAXED, __HIP_MEMORY_SCOPE_AGENT);
    }
  }
}

// ---------------- LN2: out = LN(xn + h_last) fp32 ----------------
__global__ __launch_bounds__(256) void ln2_kernel(const u16* __restrict__ xn,
    const float* __restrict__ h_last, const float* __restrict__ gam,
    const float* __restrict__ bet, float* __restrict__ out) {
  int row = blockIdx.x; int tid = threadIdx.x;
  int bi = row >> 9;
  ushort4v xv = *(const ushort4v*)(xn + (size_t)row * D_ + tid * 4);
  float4 hv = *(const float4*)(h_last + (size_t)bi * D_ + tid * 4);
  float s0 = bf2f(xv.x) + hv.x;
  float s1 = bf2f(xv.y) + hv.y;
  float s2 = bf2f(xv.z) + hv.z;
  float s3 = bf2f(xv.w) + hv.w;
  float s = s0 + s1 + s2 + s3;
  float ss = s0*s0 + s1*s1 + s2*s2 + s3*s3;
  #pragma unroll
  for (int o = 32; o > 0; o >>= 1) { s += __shfl_down(s, o); ss += __shfl_down(ss, o); }
  __shared__ float red[8];
  int w = tid >> 6, l = tid & 63;
  if (l == 0) { red[w] = s; red[4 + w] = ss; }
  __syncthreads();
  s  = red[0] + red[1] + red[2] + red[3];
  ss = red[4] + red[5] + red[6] + red[7];
  float mean = s * (1.f / D_);
  float var  = ss * (1.f / D_) - mean * mean;
  float rstd = rsqrtf(var + 1e-3f);
  float4 g = *(const float4*)(gam + tid * 4);
  float4 b = *(const float4*)(bet + tid * 4);
  float4 o4;
  o4.x = (s0 - mean) * rstd * g.x + b.x;
  o4.y = (s1 - mean) * rstd * g.y + b.y;
  o4.z = (s2 - mean) * rstd * g.z + b.z;
  o4.w = (s3 - mean) * rstd * g.w + b.w;
  *(float4*)(out + (size_t)row * D_ + tid * 4) = o4;
}

extern "C" void kernel_launch(void* const* d_in, const int* in_sizes, int n_in,
                              void* d_out, int out_size, void* d_ws, size_t ws_size,
                              hipStream_t stream) {
  const float* x    = (const float*)d_in[0];
  const float* g1   = (const float*)d_in[1];
  const float* b1   = (const float*)d_in[2];
  const float* Wk   = (const float*)d_in[3];
  const float* Wr   = (const float*)d_in[4];
  const float* bias = (const float*)d_in[5];
  const float* g2   = (const float*)d_in[6];
  const float* b2   = (const float*)d_in[7];
  char* ws = (char*)d_ws;
  u16* xn    = (u16*)(ws + OFF_XN);
  u16* Zx    = (u16*)(ws + OFF_ZX);
  u16* KT    = (u16*)(ws + OFF_KT);
  u16* RT    = (u16*)(ws + OFF_RT);
  u16* hbuf  = (u16*)(ws + OFF_HB);
  u32* flg   = (u32*)(ws + OFF_FLG);
  float* hl  = (float*)(ws + OFF_KT);    // aliases KT (dead after gemm_xk)
  float* out = (float*)d_out;

  init_kernel<<<128, 256, 0, stream>>>((u32*)hbuf, flg);
  ln1_kernel<<<B_ * T_, 256, 0, stream>>>(x, g1, b1, xn);
  transpose_bf16<<<dim3(128, 32), dim3(32, 8), 0, stream>>>(Wk, KT);
  transpose_bf16<<<dim3(128, 32), dim3(32, 8), 0, stream>>>(Wr, RT);
  gemm_xk<<<4096, 256, 0, stream>>>(xn, KT, bias, Zx);
  lstm_scan<<<NWG, 512, 0, stream>>>(Zx, RT, hbuf, hl, flg);
  ln2_kernel<<<B_ * T_, 256, 0, stream>>>(xn, hl, g2, b2, out);
}